// Round 3
// baseline (330.074 us; speedup 1.0000x reference)
//
#include <hip/hip_runtime.h>
#include <math.h>

typedef float f32x4 __attribute__((ext_vector_type(4)));
typedef short s16x8 __attribute__((ext_vector_type(8)));

#define L2E 1.4426950408889634f
#define C2L2E 2.885390081777927f  // 2*log2(e)

__device__ __forceinline__ void bf16_split_rne(float v, unsigned short& h,
                                               unsigned short& l) {
  unsigned u = __float_as_uint(v);
  unsigned hb = (u + 0x7fffu + ((u >> 16) & 1u)) >> 16;  // RNE hi
  float r = v - __uint_as_float(hb << 16);               // exact residual
  unsigned ul = __float_as_uint(r);
  unsigned lb = (ul + 0x7fffu + ((ul >> 16) & 1u)) >> 16;  // RNE lo
  h = (unsigned short)hb;
  l = (unsigned short)lb;
}

// ---------------- K0a: W^T (fp32) for coalesced G-build reads ---------------
__global__ void k0a_wt(const float* __restrict__ W, float* __restrict__ Wt) {
  int t = blockIdx.x * 256 + threadIdx.x;  // 16384
  int k = t >> 7, e = t & 127;
  Wt[e * 128 + k] = W[k * 128 + e];
}

// ---------------- K0b: x -> bf16 hi/lo in A-fragment order ------------------
// Xs[((b*16+jt)*4+ks)*1024 + hl*512 + lane*8 + q]:
//   row j = jt*16+(lane&15), k = ks*32+(lane>>4)*8+q
__global__ void k0b_xs(const float* __restrict__ x,
                       unsigned short* __restrict__ Xs) {
  int t = blockIdx.x * 256 + threadIdx.x;  // 65536 threads
  int lane = t & 63, ks = (t >> 6) & 3, jt = (t >> 8) & 15, b = t >> 12;
  int j = jt * 16 + (lane & 15);
  int k0 = ks * 32 + (lane >> 4) * 8;
  const float* xp = x + ((size_t)(b * 256 + j)) * 128 + k0;
  float4 a0 = *(const float4*)xp;
  float4 a1 = *(const float4*)(xp + 4);
  float v[8] = {a0.x, a0.y, a0.z, a0.w, a1.x, a1.y, a1.z, a1.w};
  uint4 hv, lv;
  unsigned short* hp = (unsigned short*)&hv;
  unsigned short* lp = (unsigned short*)&lv;
#pragma unroll
  for (int q = 0; q < 8; ++q) bf16_split_rne(v[q], hp[q], lp[q]);
  size_t base = (size_t)(t >> 6) * 1024 + lane * 8;
  *(uint4*)&Xs[base] = hv;
  *(uint4*)&Xs[base + 512] = lv;
}

// ---------------- K1: logits via X_split @ G_i, symmetric-skip --------------
// block=(i,b), 512 thr (8 waves): wave w -> jg=w&1 (2 j-tiles), eg=w>>1 (2 e-tiles)
// G_i = diag(x_i) W, built once into LDS (hi/lo). A-quarters (64 j) reg-dbuf'd.
// Only quarters qd >= i>>6 computed; symmetric mirror write.
__global__ __launch_bounds__(512, 2) void k1_logits(
    const float* __restrict__ x, const float* __restrict__ Wt,
    const unsigned short* __restrict__ Xs, const float* __restrict__ apb,
    const float* __restrict__ av, float* __restrict__ Lg) {
  __shared__ __align__(16) unsigned short sGh[16384];
  __shared__ __align__(16) unsigned short sGl[16384];
  __shared__ __align__(16) unsigned short sA[2][16384];
  __shared__ float sPart[4 * 4 * 4 * 16];  // [qd][jt_in_q][eg][j]

  const int tid = threadIdx.x;
  const int i = blockIdx.x, b = blockIdx.y;
  const int q0 = i >> 6;

  // ---- build G_i hi/lo into LDS (frag order) ----
  {
    const float* xi = x + ((size_t)(b * 256 + i)) * 128;
    const int fs = tid >> 4;            // 0..31 = et*4+ks
    const int et = fs >> 2, ks = fs & 3;
#pragma unroll
    for (int dl = 0; dl < 4; ++dl) {
      int l = (tid & 15) * 4 + dl;  // lane 0..63
      int e = et * 16 + (l & 15);
      int kb = ks * 32 + (l >> 4) * 8;
      float4 w0 = *(const float4*)&Wt[e * 128 + kb];
      float4 w1 = *(const float4*)&Wt[e * 128 + kb + 4];
      float4 c0 = *(const float4*)&xi[kb];
      float4 c1 = *(const float4*)&xi[kb + 4];
      float g[8] = {w0.x * c0.x, w0.y * c0.y, w0.z * c0.z, w0.w * c0.w,
                    w1.x * c1.x, w1.y * c1.y, w1.z * c1.z, w1.w * c1.w};
      uint4 hv, lv;
      unsigned short* hp = (unsigned short*)&hv;
      unsigned short* lp = (unsigned short*)&lv;
#pragma unroll
      for (int q = 0; q < 8; ++q) bf16_split_rne(g[q], hp[q], lp[q]);
      *(uint4*)&sGh[fs * 512 + l * 8] = hv;
      *(uint4*)&sGl[fs * 512 + l * 8] = lv;
    }
  }

  const int lane = tid & 63;
  const int w = tid >> 6;
  const int jg = w & 1, eg = w >> 1;
  const int quad = lane >> 4, col = lane & 15;

  float bias[2], vw[2];
#pragma unroll
  for (int ee = 0; ee < 2; ++ee) {
    int e = (eg * 2 + ee) * 16 + col;
    bias[ee] = apb[e];
    vw[ee] = av[e];
  }

  const uint4* XsB = (const uint4*)(Xs + (size_t)b * 65536);  // 4096 uint4/quarter... 1024/qtr*? (16384 shorts = 2048 uint4 per quarter)
  uint4 rg[4];
  {  // preload quarter q0
    const uint4* src = XsB + (size_t)q0 * 2048;
#pragma unroll
    for (int r = 0; r < 4; ++r) rg[r] = src[r * 512 + tid];
  }

  int par = 0;
  for (int qd = q0; qd < 4; ++qd) {
    // store staged regs, start next load
    {
      uint4* dst = (uint4*)sA[par];
#pragma unroll
      for (int r = 0; r < 4; ++r) dst[r * 512 + tid] = rg[r];
    }
    if (qd + 1 < 4) {
      const uint4* src = XsB + (size_t)(qd + 1) * 2048;
#pragma unroll
      for (int r = 0; r < 4; ++r) rg[r] = src[r * 512 + tid];
    }
    __syncthreads();  // buf[par] ready; prior compute on buf[par] done

    f32x4 acc[2][2];
#pragma unroll
    for (int jj = 0; jj < 2; ++jj)
#pragma unroll
      for (int ee = 0; ee < 2; ++ee)
        acc[jj][ee] = (f32x4){bias[ee], bias[ee], bias[ee], bias[ee]};

#pragma unroll
    for (int ks = 0; ks < 4; ++ks) {
      s16x8 gh[2], gl[2];
#pragma unroll
      for (int ee = 0; ee < 2; ++ee) {
        int fs = (eg * 2 + ee) * 4 + ks;
        gh[ee] = *(const s16x8*)&sGh[fs * 512 + lane * 8];
        gl[ee] = *(const s16x8*)&sGl[fs * 512 + lane * 8];
      }
#pragma unroll
      for (int jj = 0; jj < 2; ++jj) {
        int jtq = jg * 2 + jj;
        const unsigned short* ap = &sA[par][(jtq * 4 + ks) * 1024 + lane * 8];
        s16x8 ah = *(const s16x8*)ap;
        s16x8 al = *(const s16x8*)(ap + 512);
#pragma unroll
        for (int ee = 0; ee < 2; ++ee) {
          acc[jj][ee] = __builtin_amdgcn_mfma_f32_16x16x32_bf16(ah, gh[ee], acc[jj][ee], 0, 0, 0);
          acc[jj][ee] = __builtin_amdgcn_mfma_f32_16x16x32_bf16(al, gh[ee], acc[jj][ee], 0, 0, 0);
          acc[jj][ee] = __builtin_amdgcn_mfma_f32_16x16x32_bf16(ah, gl[ee], acc[jj][ee], 0, 0, 0);
        }
      }
    }

    // epilogue: tanh -> dot with v over this wave's 32 e -> partial per (jt,j)
#pragma unroll
    for (int jj = 0; jj < 2; ++jj) {
      float ls[4] = {0.f, 0.f, 0.f, 0.f};
#pragma unroll
      for (int ee = 0; ee < 2; ++ee) {
#pragma unroll
        for (int r = 0; r < 4; ++r) {
          float e2 = __builtin_amdgcn_exp2f(acc[jj][ee][r] * C2L2E);
          float t = 1.0f - 2.0f * __builtin_amdgcn_rcpf(e2 + 1.0f);
          ls[r] += t * vw[ee];
        }
      }
#pragma unroll
      for (int m = 1; m < 16; m <<= 1) {
        ls[0] += __shfl_xor(ls[0], m);
        ls[1] += __shfl_xor(ls[1], m);
        ls[2] += __shfl_xor(ls[2], m);
        ls[3] += __shfl_xor(ls[3], m);
      }
      if (col == 0) {
        int jt = jg * 2 + jj;
#pragma unroll
        for (int r = 0; r < 4; ++r)
          sPart[((qd * 4 + jt) * 4 + eg) * 16 + quad * 4 + r] = ls[r];
      }
    }
    par ^= 1;
  }
  __syncthreads();

  // writeout: sum eg partials, mirror-write (logits symmetric in i,j)
  if (tid < 256) {
    int q = tid >> 6;
    if (q >= q0) {
      int jin = tid & 63;
      int base = ((q * 4 + (jin >> 4)) * 4) * 16 + (jin & 15);
      float val = sPart[base] + sPart[base + 16] + sPart[base + 32] + sPart[base + 48];
      int j = q * 64 + jin;
      Lg[((size_t)(b * 256 + j)) * 256 + i] = val;
      Lg[((size_t)(b * 256 + i)) * 256 + j] = val;
    }
  }
}

// ---------------- K2: softmax over i (rows of Lg[b][j][i]), in place --------
__global__ void k2_softmax(float* __restrict__ Lg) {
  const int w = threadIdx.x >> 6, lane = threadIdx.x & 63;
  const int row = blockIdx.x * 4 + w;
  float4* p = (float4*)(Lg + (size_t)row * 256);
  float4 v = p[lane];
  float m = fmaxf(fmaxf(v.x, v.y), fmaxf(v.z, v.w));
#pragma unroll
  for (int mask = 1; mask < 64; mask <<= 1) m = fmaxf(m, __shfl_xor(m, mask));
  v.x = __builtin_amdgcn_exp2f((v.x - m) * L2E);
  v.y = __builtin_amdgcn_exp2f((v.y - m) * L2E);
  v.z = __builtin_amdgcn_exp2f((v.z - m) * L2E);
  v.w = __builtin_amdgcn_exp2f((v.w - m) * L2E);
  float s = v.x + v.y + v.z + v.w;
#pragma unroll
  for (int mask = 1; mask < 64; mask <<= 1) s += __shfl_xor(s, mask);
  float inv = 1.0f / s;
  v.x *= inv; v.y *= inv; v.z *= inv; v.w *= inv;
  p[lane] = v;
}

// ---------------- K34: agg (fp32, LDS, vectorized) + h (fp64 acc) -----------
__global__ void k34_aggh(const float* __restrict__ Lg, const float* __restrict__ x,
                         const float* __restrict__ pwa, const float* __restrict__ pwoa,
                         const float* __restrict__ pwab, const float* __restrict__ pwob,
                         const float* __restrict__ gam, const float* __restrict__ bet,
                         const float* __restrict__ mea, const float* __restrict__ varr,
                         float* __restrict__ h) {
  const int b = blockIdx.y, i0 = blockIdx.x * 16;
  const int tid = threadIdx.x;
  const int il = tid >> 4, d0 = (tid & 15) * 8;
  __shared__ float satt[16][17];
  __shared__ float sxj[2048];
  __shared__ float sa[2048];
  __shared__ float sxi[2048];

  const float4* xs = (const float4*)(x + ((size_t)(b * 256 + i0)) * 128);
  ((float4*)sxi)[tid] = xs[tid];
  ((float4*)sxi)[tid + 256] = xs[tid + 256];

  float acc[8] = {0.f, 0.f, 0.f, 0.f, 0.f, 0.f, 0.f, 0.f};
  for (int jj = 0; jj < 256; jj += 16) {
    __syncthreads();
    satt[tid >> 4][tid & 15] =
        Lg[((size_t)(b * 256 + jj + (tid >> 4))) * 256 + i0 + (tid & 15)];
    const float4* xsrc = (const float4*)(x + ((size_t)(b * 256 + jj)) * 128);
    ((float4*)sxj)[tid] = xsrc[tid];
    ((float4*)sxj)[tid + 256] = xsrc[tid + 256];
    __syncthreads();
#pragma unroll
    for (int jl = 0; jl < 16; ++jl) {
      float a = satt[jl][il];
      float4 x0 = *(const float4*)&sxj[jl * 128 + d0];
      float4 x1 = *(const float4*)&sxj[jl * 128 + d0 + 4];
      acc[0] += a * x0.x; acc[1] += a * x0.y;
      acc[2] += a * x0.z; acc[3] += a * x0.w;
      acc[4] += a * x1.x; acc[5] += a * x1.y;
      acc[6] += a * x1.z; acc[7] += a * x1.w;
    }
  }
  __syncthreads();
#pragma unroll
  for (int q = 0; q < 8; ++q) sa[il * 128 + d0 + q] = acc[q];
  __syncthreads();

  double z[8] = {0, 0, 0, 0, 0, 0, 0, 0};
  for (int k = 0; k < 128; ++k) {
    double a = (double)sa[il * 128 + k];
    const float4* wr = (const float4*)(pwa + k * 128 + d0);
    float4 w0 = wr[0], w1 = wr[1];
    z[0] += a * (double)w0.x; z[1] += a * (double)w0.y;
    z[2] += a * (double)w0.z; z[3] += a * (double)w0.w;
    z[4] += a * (double)w1.x; z[5] += a * (double)w1.y;
    z[6] += a * (double)w1.z; z[7] += a * (double)w1.w;
  }
  for (int k = 0; k < 128; ++k) {
    double a = (double)sxi[il * 128 + k];
    const float4* wr = (const float4*)(pwoa + k * 128 + d0);
    float4 w0 = wr[0], w1 = wr[1];
    z[0] += a * (double)w0.x; z[1] += a * (double)w0.y;
    z[2] += a * (double)w0.z; z[3] += a * (double)w0.w;
    z[4] += a * (double)w1.x; z[5] += a * (double)w1.y;
    z[6] += a * (double)w1.z; z[7] += a * (double)w1.w;
  }
  float* dst = h + ((size_t)(b * 256 + i0 + il)) * 128 + d0;
#pragma unroll
  for (int q = 0; q < 8; ++q) {
    int d = d0 + q;
    double hv = z[q] + (double)pwab[d] + (double)pwob[d];
    double bn = (hv - (double)mea[d]) * (1.0 / sqrt((double)varr[d] + 1e-5)) *
                    (double)gam[d] +
                (double)bet[d];
    float bf = (float)bn;
    float se = bf > 0.f ? 1.0507009873554805f * bf
                        : 1.7580993408473766f *
                              (__builtin_amdgcn_exp2f(bf * L2E) - 1.0f);
    dst[q] = se;
  }
}

// ---------------- K5: scores (fp64), stable top-128, gather h*score ---------
__global__ void k5_topk(const float* __restrict__ h, const float* __restrict__ plw,
                        const float* __restrict__ plb, float* __restrict__ out) {
  const int b = blockIdx.x, t = threadIdx.x;
  __shared__ float sc[256];
  __shared__ int sel[128];
  const float* hr = h + ((size_t)(b * 256 + t)) * 128;
  double z = 0.0;
  for (int k = 0; k < 128; ++k) z += (double)hr[k] * (double)plw[k];
  z += (double)plb[0];
  sc[t] = (float)(1.0 / (1.0 + exp(-z)));
  __syncthreads();
  const float st = sc[t];
  int rank = 0;
  for (int m = 0; m < 256; ++m) {
    float sm = sc[m];
    rank += (sm > st) || (sm == st && m < t);  // stable descending
  }
  if (rank < 128) sel[rank] = t;
  __syncthreads();
  const float4* h4 = (const float4*)(h + (size_t)b * 256 * 128);
  float4* o4 = (float4*)(out + (size_t)b * 128 * 128);
#pragma unroll
  for (int r = 0; r < 16; ++r) {
    int v = t + 256 * r;
    int row = v >> 5, q = v & 31;
    int src = sel[row];
    float ss = sc[src];
    float4 hv = h4[src * 32 + q];
    float4 ov;
    ov.x = hv.x * ss; ov.y = hv.y * ss; ov.z = hv.z * ss; ov.w = hv.w * ss;
    o4[row * 32 + q] = ov;
  }
}

extern "C" void kernel_launch(void* const* d_in, const int* in_sizes, int n_in,
                              void* d_out, int out_size, void* d_ws, size_t ws_size,
                              hipStream_t stream) {
  const float* x    = (const float*)d_in[0];
  const float* apw  = (const float*)d_in[1];
  const float* apb  = (const float*)d_in[2];
  const float* av   = (const float*)d_in[3];
  const float* pwa  = (const float*)d_in[4];
  const float* pwab = (const float*)d_in[5];
  const float* pwoa = (const float*)d_in[6];
  const float* pwob = (const float*)d_in[7];
  const float* gam  = (const float*)d_in[8];
  const float* bet  = (const float*)d_in[9];
  const float* mea  = (const float*)d_in[10];
  const float* varr = (const float*)d_in[11];
  const float* plw  = (const float*)d_in[12];
  const float* plb  = (const float*)d_in[13];
  float* out = (float*)d_out;

  // ws: Wt (64KB) | Xs (2MB) | Lg (4MB) | h (2MB)
  float* Wt = (float*)d_ws;
  unsigned short* Xs = (unsigned short*)((char*)d_ws + 65536);
  float* Lg = (float*)((char*)d_ws + 65536 + 2097152);
  float* hb = Lg + (size_t)16 * 256 * 256;

  k0a_wt<<<64, 256, 0, stream>>>(apw, Wt);
  k0b_xs<<<256, 256, 0, stream>>>(x, Xs);
  k1_logits<<<dim3(256, 16), 512, 0, stream>>>(x, Wt, Xs, apb, av, Lg);
  k2_softmax<<<1024, 256, 0, stream>>>(Lg);
  k34_aggh<<<dim3(16, 16), 256, 0, stream>>>(Lg, x, pwa, pwoa, pwab, pwob, gam,
                                             bet, mea, varr, hb);
  k5_topk<<<16, 256, 0, stream>>>(hb, plw, plb, out);
}

// Round 4
// 189.241 us; speedup vs baseline: 1.7442x; 1.7442x over previous
//
#include <hip/hip_runtime.h>
#include <math.h>

typedef float f32x4 __attribute__((ext_vector_type(4)));
typedef short s16x8 __attribute__((ext_vector_type(8)));

#define L2E 1.4426950408889634f
#define C2L2E 2.885390081777927f  // 2*log2(e)

// ---------------- K0: W -> bf16 hi/lo, W^T layout, XOR-swizzled -------------
// addr = e*128 + (d ^ ((e&7)<<3));  hi/lo both RNE (same as R1, verified)
__global__ void k0_prep(const float* __restrict__ W,
                        unsigned short* __restrict__ gWhi,
                        unsigned short* __restrict__ gWlo) {
  int t = blockIdx.x * 256 + threadIdx.x;  // 0..16383
  int d = t >> 7, e = t & 127;
  float w = W[d * 128 + e];
  unsigned u = __float_as_uint(w);
  unsigned hb = (u + 0x7fffu + ((u >> 16) & 1u)) >> 16;
  float r = w - __uint_as_float(hb << 16);
  unsigned ul = __float_as_uint(r);
  unsigned lb = (ul + 0x7fffu + ((ul >> 16) & 1u)) >> 16;
  int addr = e * 128 + (d ^ ((e & 7) << 3));
  gWhi[addr] = (unsigned short)hb;
  gWlo[addr] = (unsigned short)lb;
}

// ---------------- K1: logits, triangular tile grid + mirror write -----------
// block covers 16 i x 16 j (4 waves, mt=4 i's each); only tiles tj >= ti.
// A = (xj ⊙ xi) split hi/lo via packed v_perm; B = W hi/lo from LDS.
__global__ __launch_bounds__(256, 2) void k1_logits(
    const float* __restrict__ x, const unsigned short* __restrict__ gWhi,
    const unsigned short* __restrict__ gWlo, const float* __restrict__ apb,
    const float* __restrict__ av, float* __restrict__ Lg) {
  __shared__ __align__(16) unsigned short sWhi[16384];
  __shared__ __align__(16) unsigned short sWlo[16384];
  __shared__ __align__(16) float sXj[16 * 132];

  // triangular map: blockIdx.x in [0,136) -> (ti, tj), ti <= tj
  int tt = blockIdx.x, ti = 0;
  while (tt >= 16 - ti) { tt -= 16 - ti; ++ti; }
  const int tj = ti + tt;
  const int b = blockIdx.y;
  const int i0 = ti * 16, j0 = tj * 16;
  const int tid = threadIdx.x;

  {  // stage W hi/lo (pre-swizzled, pure copy) + x_j rows
    const uint4* shi = (const uint4*)gWhi;
    const uint4* slo = (const uint4*)gWlo;
    uint4* dhi = (uint4*)sWhi;
    uint4* dlo = (uint4*)sWlo;
#pragma unroll
    for (int r = 0; r < 8; ++r) {
      dhi[tid + 256 * r] = shi[tid + 256 * r];
      dlo[tid + 256 * r] = slo[tid + 256 * r];
    }
    const float4* xsrc = (const float4*)(x + ((size_t)(b * 256 + j0)) * 128);
#pragma unroll
    for (int r = 0; r < 2; ++r) {
      int v = tid + 256 * r;
      *(float4*)&sXj[(v >> 5) * 132 + (v & 31) * 4] = xsrc[v];
    }
  }
  __syncthreads();

  const int lane = tid & 63;
  const int w = tid >> 6;
  const int quad = lane >> 4;
  const int col = lane & 15;
  const int swz = (col & 7) << 3;

  float vw[8];
  f32x4 acc[4][8];
#pragma unroll
  for (int et = 0; et < 8; ++et) {
    float bi = apb[col + 16 * et];
    vw[et] = av[col + 16 * et];
#pragma unroll
    for (int mt = 0; mt < 4; ++mt) acc[mt][et] = (f32x4){bi, bi, bi, bi};
  }

  const float* xib = x + ((size_t)(b * 256 + i0 + 4 * w)) * 128;

#pragma unroll
  for (int kstep = 0; kstep < 4; ++kstep) {
    const int k0 = kstep * 32 + quad * 8;
    float4 xj0 = *(const float4*)&sXj[col * 132 + k0];
    float4 xj1 = *(const float4*)&sXj[col * 132 + k0 + 4];
    s16x8 Ah[4], Al[4];
#pragma unroll
    for (int mt = 0; mt < 4; ++mt) {
      const float* xip = xib + mt * 128 + k0;
      float4 xi0 = *(const float4*)xip;  // broadcast across 16 cols -> L1
      float4 xi1 = *(const float4*)(xip + 4);
      float pv[8];
      pv[0] = xi0.x * xj0.x; pv[1] = xi0.y * xj0.y;
      pv[2] = xi0.z * xj0.z; pv[3] = xi0.w * xj0.w;
      pv[4] = xi1.x * xj1.x; pv[5] = xi1.y * xj1.y;
      pv[6] = xi1.z * xj1.z; pv[7] = xi1.w * xj1.w;
      uint4 hp, lp;
      unsigned* hq = (unsigned*)&hp;
      unsigned* lq = (unsigned*)&lp;
#pragma unroll
      for (int p = 0; p < 4; ++p) {
        unsigned u0 = __float_as_uint(pv[2 * p]);
        unsigned u1 = __float_as_uint(pv[2 * p + 1]);
        hq[p] = __builtin_amdgcn_perm(u1, u0, 0x07060302);  // {hi16(u1),hi16(u0)}
        float h0 = __uint_as_float(u0 & 0xffff0000u);
        float h1 = __uint_as_float(u1 & 0xffff0000u);
        unsigned v0 = __float_as_uint(pv[2 * p] - h0) + 0x8000u;
        unsigned v1 = __float_as_uint(pv[2 * p + 1] - h1) + 0x8000u;
        lq[p] = __builtin_amdgcn_perm(v1, v0, 0x07060302);
      }
      Ah[mt] = *(s16x8*)&hp;
      Al[mt] = *(s16x8*)&lp;
    }
#pragma unroll
    for (int et = 0; et < 8; ++et) {
      const int addr = (col + 16 * et) * 128 + (k0 ^ swz);
      s16x8 bh = *(const s16x8*)&sWhi[addr];
      s16x8 bl = *(const s16x8*)&sWlo[addr];
#pragma unroll
      for (int mt = 0; mt < 4; ++mt) {
        acc[mt][et] = __builtin_amdgcn_mfma_f32_16x16x32_bf16(Ah[mt], bh, acc[mt][et], 0, 0, 0);
        acc[mt][et] = __builtin_amdgcn_mfma_f32_16x16x32_bf16(Al[mt], bh, acc[mt][et], 0, 0, 0);
        acc[mt][et] = __builtin_amdgcn_mfma_f32_16x16x32_bf16(Ah[mt], bl, acc[mt][et], 0, 0, 0);
      }
    }
  }

  // epilogue: tanh -> v-dot over e (8 et in-lane + 16-col butterfly)
  float fl[4];
#pragma unroll
  for (int mt = 0; mt < 4; ++mt) {
    float ls[4] = {0.f, 0.f, 0.f, 0.f};
#pragma unroll
    for (int et = 0; et < 8; ++et) {
#pragma unroll
      for (int r = 0; r < 4; ++r) {
        float e2 = __builtin_amdgcn_exp2f(acc[mt][et][r] * C2L2E);
        float t = 1.0f - 2.0f * __builtin_amdgcn_rcpf(e2 + 1.0f);
        ls[r] += t * vw[et];
      }
    }
#pragma unroll
    for (int m = 1; m < 16; m <<= 1) {
      ls[0] += __shfl_xor(ls[0], m);
      ls[1] += __shfl_xor(ls[1], m);
      ls[2] += __shfl_xor(ls[2], m);
      ls[3] += __shfl_xor(ls[3], m);
    }
    fl[mt] = (col == 0) ? ls[0] : (col == 1) ? ls[1] : (col == 2) ? ls[2] : ls[3];
  }
  if (col < 4) {
    const int j = j0 + quad * 4 + col;
    float4 val = {fl[0], fl[1], fl[2], fl[3]};
    *(float4*)&Lg[((size_t)(b * 256 + j)) * 256 + i0 + 4 * w] = val;
    if (ti != tj) {  // mirror (bitwise-identical by symmetry)
#pragma unroll
      for (int mt = 0; mt < 4; ++mt)
        Lg[((size_t)(b * 256 + i0 + 4 * w + mt)) * 256 + j] = fl[mt];
    }
  }
}

// ---------------- K2: softmax over i (rows of Lg[b][j][i]), in place --------
__global__ void k2_softmax(float* __restrict__ Lg) {
  const int w = threadIdx.x >> 6, lane = threadIdx.x & 63;
  const int row = blockIdx.x * 4 + w;
  float4* p = (float4*)(Lg + (size_t)row * 256);
  float4 v = p[lane];
  float m = fmaxf(fmaxf(v.x, v.y), fmaxf(v.z, v.w));
#pragma unroll
  for (int mask = 1; mask < 64; mask <<= 1) m = fmaxf(m, __shfl_xor(m, mask));
  v.x = __builtin_amdgcn_exp2f((v.x - m) * L2E);
  v.y = __builtin_amdgcn_exp2f((v.y - m) * L2E);
  v.z = __builtin_amdgcn_exp2f((v.z - m) * L2E);
  v.w = __builtin_amdgcn_exp2f((v.w - m) * L2E);
  float s = v.x + v.y + v.z + v.w;
#pragma unroll
  for (int mask = 1; mask < 64; mask <<= 1) s += __shfl_xor(s, mask);
  float inv = 1.0f / s;
  v.x *= inv; v.y *= inv; v.z *= inv; v.w *= inv;
  p[lane] = v;
}

// ---------------- K34: agg (fp32) + h (fp64 acc), 8-i tiles, 512 blocks -----
__global__ void k34_aggh(const float* __restrict__ Lg, const float* __restrict__ x,
                         const float* __restrict__ pwa, const float* __restrict__ pwoa,
                         const float* __restrict__ pwab, const float* __restrict__ pwob,
                         const float* __restrict__ gam, const float* __restrict__ bet,
                         const float* __restrict__ mea, const float* __restrict__ varr,
                         float* __restrict__ h) {
  const int b = blockIdx.y, i0 = blockIdx.x * 8;
  const int tid = threadIdx.x;
  const int il = tid >> 5, dl = tid & 31;  // 8 i x 32 d-chunks
  __shared__ float satt[16][8];
  __shared__ float sxj[2048];
  __shared__ float sa[1024];
  __shared__ float sxi[1024];

  ((float4*)sxi)[tid] = ((const float4*)(x + ((size_t)(b * 256 + i0)) * 128))[tid];

  float acc[4] = {0.f, 0.f, 0.f, 0.f};
  for (int jj = 0; jj < 256; jj += 16) {
    __syncthreads();
    if (tid < 128)
      satt[tid >> 3][tid & 7] =
          Lg[((size_t)(b * 256 + jj + (tid >> 3))) * 256 + i0 + (tid & 7)];
    const float4* xsrc = (const float4*)(x + ((size_t)(b * 256 + jj)) * 128);
    ((float4*)sxj)[tid] = xsrc[tid];
    ((float4*)sxj)[tid + 256] = xsrc[tid + 256];
    __syncthreads();
#pragma unroll
    for (int jl = 0; jl < 16; ++jl) {
      float a = satt[jl][il];
      float4 xv = *(const float4*)&sxj[jl * 128 + dl * 4];
      acc[0] += a * xv.x; acc[1] += a * xv.y;
      acc[2] += a * xv.z; acc[3] += a * xv.w;
    }
  }
  __syncthreads();
  *(float4*)&sa[il * 128 + dl * 4] = *(float4*)acc;
  __syncthreads();

  double z[4] = {0, 0, 0, 0};
  for (int k = 0; k < 128; ++k) {
    double a = (double)sa[il * 128 + k];
    float4 wv = *(const float4*)(pwa + k * 128 + dl * 4);
    z[0] += a * (double)wv.x; z[1] += a * (double)wv.y;
    z[2] += a * (double)wv.z; z[3] += a * (double)wv.w;
  }
  for (int k = 0; k < 128; ++k) {
    double a = (double)sxi[il * 128 + k];
    float4 wv = *(const float4*)(pwoa + k * 128 + dl * 4);
    z[0] += a * (double)wv.x; z[1] += a * (double)wv.y;
    z[2] += a * (double)wv.z; z[3] += a * (double)wv.w;
  }
  float* dst = h + ((size_t)(b * 256 + i0 + il)) * 128 + dl * 4;
  float o[4];
#pragma unroll
  for (int q = 0; q < 4; ++q) {
    int d = dl * 4 + q;
    double hv = z[q] + (double)pwab[d] + (double)pwob[d];
    double bn = (hv - (double)mea[d]) * (1.0 / sqrt((double)varr[d] + 1e-5)) *
                    (double)gam[d] +
                (double)bet[d];
    float bf = (float)bn;
    o[q] = bf > 0.f ? 1.0507009873554805f * bf
                    : 1.7580993408473766f *
                          (__builtin_amdgcn_exp2f(bf * L2E) - 1.0f);
  }
  *(float4*)dst = *(float4*)o;
}

// ---------------- K5: scores (fp64 chunked), stable top-128, gather ---------
__global__ __launch_bounds__(1024) void k5_topk(const float* __restrict__ h,
                                                const float* __restrict__ plw,
                                                const float* __restrict__ plb,
                                                float* __restrict__ out) {
  const int b = blockIdx.x, tid = threadIdx.x;
  const int t = tid >> 2, c = tid & 3;  // node, chunk
  __shared__ double part[256][4];
  __shared__ int ipart[256][4];
  __shared__ float sc[256];
  __shared__ int sel[128];

  {
    const float* hr = h + ((size_t)(b * 256 + t)) * 128 + c * 32;
    const float* wr = plw + c * 32;
    double z = 0.0;
    for (int k = 0; k < 32; ++k) z += (double)hr[k] * (double)wr[k];
    part[t][c] = z;
  }
  __syncthreads();
  if (c == 0) {
    double zz = part[t][0] + part[t][1] + part[t][2] + part[t][3] + (double)plb[0];
    sc[t] = (float)(1.0 / (1.0 + exp(-zz)));
  }
  __syncthreads();
  {
    const float st = sc[t];
    int r = 0;
    for (int m = c * 64; m < c * 64 + 64; ++m) {
      float sm = sc[m];
      r += (sm > st) || (sm == st && m < t);  // stable descending
    }
    ipart[t][c] = r;
  }
  __syncthreads();
  if (c == 0) {
    int rank = ipart[t][0] + ipart[t][1] + ipart[t][2] + ipart[t][3];
    if (rank < 128) sel[rank] = t;
  }
  __syncthreads();
  const float4* h4 = (const float4*)(h + (size_t)b * 256 * 128);
  float4* o4 = (float4*)(out + (size_t)b * 128 * 128);
#pragma unroll
  for (int r = 0; r < 4; ++r) {
    int v = tid + 1024 * r;  // 0..4095
    int row = v >> 5, q = v & 31;
    int src = sel[row];
    float ss = sc[src];
    float4 hv = h4[src * 32 + q];
    float4 ov;
    ov.x = hv.x * ss; ov.y = hv.y * ss; ov.z = hv.z * ss; ov.w = hv.w * ss;
    o4[row * 32 + q] = ov;
  }
}

extern "C" void kernel_launch(void* const* d_in, const int* in_sizes, int n_in,
                              void* d_out, int out_size, void* d_ws, size_t ws_size,
                              hipStream_t stream) {
  const float* x    = (const float*)d_in[0];
  const float* apw  = (const float*)d_in[1];
  const float* apb  = (const float*)d_in[2];
  const float* av   = (const float*)d_in[3];
  const float* pwa  = (const float*)d_in[4];
  const float* pwab = (const float*)d_in[5];
  const float* pwoa = (const float*)d_in[6];
  const float* pwob = (const float*)d_in[7];
  const float* gam  = (const float*)d_in[8];
  const float* bet  = (const float*)d_in[9];
  const float* mea  = (const float*)d_in[10];
  const float* varr = (const float*)d_in[11];
  const float* plw  = (const float*)d_in[12];
  const float* plb  = (const float*)d_in[13];
  float* out = (float*)d_out;

  unsigned short* gWhi = (unsigned short*)d_ws;
  unsigned short* gWlo = gWhi + 16384;
  float* Lg = (float*)((char*)d_ws + 65536);
  float* hb = Lg + (size_t)16 * 256 * 256;

  k0_prep<<<64, 256, 0, stream>>>(apw, gWhi, gWlo);
  k1_logits<<<dim3(136, 16), 256, 0, stream>>>(x, gWhi, gWlo, apb, av, Lg);
  k2_softmax<<<1024, 256, 0, stream>>>(Lg);
  k34_aggh<<<dim3(32, 16), 256, 0, stream>>>(Lg, x, pwa, pwoa, pwab, pwob, gam,
                                             bet, mea, varr, hb);
  k5_topk<<<16, 1024, 0, stream>>>(hb, plw, plb, out);
}

// Round 5
// 185.144 us; speedup vs baseline: 1.7828x; 1.0221x over previous
//
#include <hip/hip_runtime.h>
#include <math.h>

typedef float f32x4 __attribute__((ext_vector_type(4)));
typedef short s16x8 __attribute__((ext_vector_type(8)));

#define L2E 1.4426950408889634f
#define C2L2E 2.885390081777927f  // 2*log2(e)

// ---------------- K0: W -> bf16 hi/lo (W^T, XOR-swizzled) + zero S ----------
__global__ void k0_prep(const float* __restrict__ W,
                        unsigned short* __restrict__ gWhi,
                        unsigned short* __restrict__ gWlo,
                        float* __restrict__ S) {
  int bid = blockIdx.x;
  if (bid < 64) {
    int t = bid * 256 + threadIdx.x;  // 0..16383
    int d = t >> 7, e = t & 127;
    float w = W[d * 128 + e];
    unsigned u = __float_as_uint(w);
    unsigned hb = (u + 0x7fffu + ((u >> 16) & 1u)) >> 16;  // RNE hi
    float r = w - __uint_as_float(hb << 16);
    unsigned ul = __float_as_uint(r);
    unsigned lb = (ul + 0x7fffu + ((ul >> 16) & 1u)) >> 16;  // RNE lo
    int addr = e * 128 + (d ^ ((e & 7) << 3));
    gWhi[addr] = (unsigned short)hb;
    gWlo[addr] = (unsigned short)lb;
  } else {
    S[(bid - 64) * 256 + threadIdx.x] = 0.f;  // 4096 row-sum slots
  }
}

// ---------------- KA: E=exp(logit) + row sums, triangular + mirror ----------
// block covers 16 i x 16 j (4 waves, mt=4 i's each); only tiles tj >= ti.
__global__ __launch_bounds__(256, 2) void kA_logits(
    const float* __restrict__ x, const unsigned short* __restrict__ gWhi,
    const unsigned short* __restrict__ gWlo, const float* __restrict__ apb,
    const float* __restrict__ av, float* __restrict__ Lg,
    float* __restrict__ S) {
  __shared__ __align__(16) unsigned short sWhi[16384];
  __shared__ __align__(16) unsigned short sWlo[16384];
  __shared__ __align__(16) float sXj[16 * 132];
  __shared__ float sRow[16][4];
  __shared__ float sMir[16];

  int tt = blockIdx.x, ti = 0;
  while (tt >= 16 - ti) { tt -= 16 - ti; ++ti; }
  const int tj = ti + tt;
  const int b = blockIdx.y;
  const int i0 = ti * 16, j0 = tj * 16;
  const int tid = threadIdx.x;

  {  // stage W hi/lo (pre-swizzled copy) + x_j rows
    const uint4* shi = (const uint4*)gWhi;
    const uint4* slo = (const uint4*)gWlo;
    uint4* dhi = (uint4*)sWhi;
    uint4* dlo = (uint4*)sWlo;
#pragma unroll
    for (int r = 0; r < 8; ++r) {
      dhi[tid + 256 * r] = shi[tid + 256 * r];
      dlo[tid + 256 * r] = slo[tid + 256 * r];
    }
    const float4* xsrc = (const float4*)(x + ((size_t)(b * 256 + j0)) * 128);
#pragma unroll
    for (int r = 0; r < 2; ++r) {
      int v = tid + 256 * r;
      *(float4*)&sXj[(v >> 5) * 132 + (v & 31) * 4] = xsrc[v];
    }
  }
  __syncthreads();

  const int lane = tid & 63;
  const int w = tid >> 6;
  const int quad = lane >> 4;
  const int col = lane & 15;
  const int swz = (col & 7) << 3;

  float vw[8];
  f32x4 acc[4][8];
#pragma unroll
  for (int et = 0; et < 8; ++et) {
    float bi = apb[col + 16 * et];
    vw[et] = av[col + 16 * et];
#pragma unroll
    for (int mt = 0; mt < 4; ++mt) acc[mt][et] = (f32x4){bi, bi, bi, bi};
  }

  const float* xib = x + ((size_t)(b * 256 + i0 + 4 * w)) * 128;

#pragma unroll
  for (int kstep = 0; kstep < 4; ++kstep) {
    const int k0 = kstep * 32 + quad * 8;
    float4 xj0 = *(const float4*)&sXj[col * 132 + k0];
    float4 xj1 = *(const float4*)&sXj[col * 132 + k0 + 4];
    s16x8 Ah[4], Al[4];
#pragma unroll
    for (int mt = 0; mt < 4; ++mt) {
      const float* xip = xib + mt * 128 + k0;
      float4 xi0 = *(const float4*)xip;
      float4 xi1 = *(const float4*)(xip + 4);
      float pv[8];
      pv[0] = xi0.x * xj0.x; pv[1] = xi0.y * xj0.y;
      pv[2] = xi0.z * xj0.z; pv[3] = xi0.w * xj0.w;
      pv[4] = xi1.x * xj1.x; pv[5] = xi1.y * xj1.y;
      pv[6] = xi1.z * xj1.z; pv[7] = xi1.w * xj1.w;
      uint4 hp, lp;
      unsigned* hq = (unsigned*)&hp;
      unsigned* lq = (unsigned*)&lp;
#pragma unroll
      for (int p = 0; p < 4; ++p) {
        unsigned u0 = __float_as_uint(pv[2 * p]);
        unsigned u1 = __float_as_uint(pv[2 * p + 1]);
        hq[p] = __builtin_amdgcn_perm(u1, u0, 0x07060302);
        float h0 = __uint_as_float(u0 & 0xffff0000u);
        float h1 = __uint_as_float(u1 & 0xffff0000u);
        unsigned v0 = __float_as_uint(pv[2 * p] - h0) + 0x8000u;
        unsigned v1 = __float_as_uint(pv[2 * p + 1] - h1) + 0x8000u;
        lq[p] = __builtin_amdgcn_perm(v1, v0, 0x07060302);
      }
      Ah[mt] = *(s16x8*)&hp;
      Al[mt] = *(s16x8*)&lp;
    }
#pragma unroll
    for (int et = 0; et < 8; ++et) {
      const int addr = (col + 16 * et) * 128 + (k0 ^ swz);
      s16x8 bh = *(const s16x8*)&sWhi[addr];
      s16x8 bl = *(const s16x8*)&sWlo[addr];
#pragma unroll
      for (int mt = 0; mt < 4; ++mt) {
        acc[mt][et] = __builtin_amdgcn_mfma_f32_16x16x32_bf16(Ah[mt], bh, acc[mt][et], 0, 0, 0);
        acc[mt][et] = __builtin_amdgcn_mfma_f32_16x16x32_bf16(Al[mt], bh, acc[mt][et], 0, 0, 0);
        acc[mt][et] = __builtin_amdgcn_mfma_f32_16x16x32_bf16(Ah[mt], bl, acc[mt][et], 0, 0, 0);
      }
    }
  }

  // epilogue: logit -> E = exp(logit) (no max-sub; |logit|<~8 so safe)
  float E[4];
#pragma unroll
  for (int mt = 0; mt < 4; ++mt) {
    float ls[4] = {0.f, 0.f, 0.f, 0.f};
#pragma unroll
    for (int et = 0; et < 8; ++et) {
#pragma unroll
      for (int r = 0; r < 4; ++r) {
        float e2 = __builtin_amdgcn_exp2f(acc[mt][et][r] * C2L2E);
        float t = 1.0f - 2.0f * __builtin_amdgcn_rcpf(e2 + 1.0f);
        ls[r] += t * vw[et];
      }
    }
#pragma unroll
    for (int m = 1; m < 16; m <<= 1) {
      ls[0] += __shfl_xor(ls[0], m);
      ls[1] += __shfl_xor(ls[1], m);
      ls[2] += __shfl_xor(ls[2], m);
      ls[3] += __shfl_xor(ls[3], m);
    }
    float fl = (col == 0) ? ls[0] : (col == 1) ? ls[1] : (col == 2) ? ls[2] : ls[3];
    E[mt] = __builtin_amdgcn_exp2f(fl * L2E);
  }

  if (col < 4) {  // primary tile write (E for rows j in tj-tile, cols i in ti)
    const int j = j0 + quad * 4 + col;
    float4 val = {E[0], E[1], E[2], E[3]};
    *(float4*)&Lg[((size_t)(b * 256 + j)) * 256 + i0 + 4 * w] = val;
    sRow[quad * 4 + col][w] = E[0] + E[1] + E[2] + E[3];
  }

  if (ti != tj) {  // mirror write + mirror row sums
    if (col < 4) {
      const int j = j0 + quad * 4 + col;
#pragma unroll
      for (int mt = 0; mt < 4; ++mt)
        Lg[((size_t)(b * 256 + i0 + 4 * w + mt)) * 256 + j] = E[mt];
    }
#pragma unroll
    for (int mt = 0; mt < 4; ++mt) {
      float v = (col < 4) ? E[mt] : 0.f;
#pragma unroll
      for (int m = 1; m < 64; m <<= 1) v += __shfl_xor(v, m);
      if (lane == 0) sMir[4 * w + mt] = v;
    }
  }
  __syncthreads();
  if (tid < 16) {
    atomicAdd(&S[b * 256 + j0 + tid],
              sRow[tid][0] + sRow[tid][1] + sRow[tid][2] + sRow[tid][3]);
    if (ti != tj) atomicAdd(&S[b * 256 + i0 + tid], sMir[tid]);
  }
}

// ---------------- KB: agg (att=E/S) + h (fp64) + pool scores ----------------
__global__ void kB_aggh(const float* __restrict__ Lg, const float* __restrict__ S,
                        const float* __restrict__ x,
                        const float* __restrict__ pwa, const float* __restrict__ pwoa,
                        const float* __restrict__ pwab, const float* __restrict__ pwob,
                        const float* __restrict__ gam, const float* __restrict__ bet,
                        const float* __restrict__ mea, const float* __restrict__ varr,
                        const float* __restrict__ plw, const float* __restrict__ plb,
                        float* __restrict__ h, float* __restrict__ scores) {
  const int b = blockIdx.y, i0 = blockIdx.x * 8;
  const int tid = threadIdx.x;
  const int il = tid >> 5, dl = tid & 31;  // 8 i x 32 d-chunks
  __shared__ float sInv[256];
  __shared__ float satt[16][8];
  __shared__ float sxj[2048];
  __shared__ float sa[1024];
  __shared__ float sxi[1024];
  __shared__ double sScD[8][32];

  sInv[tid] = 1.0f / S[b * 256 + tid];
  ((float4*)sxi)[tid] = ((const float4*)(x + ((size_t)(b * 256 + i0)) * 128))[tid];

  float acc[4] = {0.f, 0.f, 0.f, 0.f};
  for (int jj = 0; jj < 256; jj += 16) {
    __syncthreads();
    if (tid < 128)
      satt[tid >> 3][tid & 7] =
          Lg[((size_t)(b * 256 + jj + (tid >> 3))) * 256 + i0 + (tid & 7)] *
          sInv[jj + (tid >> 3)];
    const float4* xsrc = (const float4*)(x + ((size_t)(b * 256 + jj)) * 128);
    ((float4*)sxj)[tid] = xsrc[tid];
    ((float4*)sxj)[tid + 256] = xsrc[tid + 256];
    __syncthreads();
#pragma unroll
    for (int jl = 0; jl < 16; ++jl) {
      float a = satt[jl][il];
      float4 xv = *(const float4*)&sxj[jl * 128 + dl * 4];
      acc[0] += a * xv.x; acc[1] += a * xv.y;
      acc[2] += a * xv.z; acc[3] += a * xv.w;
    }
  }
  __syncthreads();
  *(float4*)&sa[il * 128 + dl * 4] = *(float4*)acc;
  __syncthreads();

  double z[4] = {0, 0, 0, 0};
  for (int k = 0; k < 128; ++k) {
    double a = (double)sa[il * 128 + k];
    float4 wv = *(const float4*)(pwa + k * 128 + dl * 4);
    z[0] += a * (double)wv.x; z[1] += a * (double)wv.y;
    z[2] += a * (double)wv.z; z[3] += a * (double)wv.w;
  }
  for (int k = 0; k < 128; ++k) {
    double a = (double)sxi[il * 128 + k];
    float4 wv = *(const float4*)(pwoa + k * 128 + dl * 4);
    z[0] += a * (double)wv.x; z[1] += a * (double)wv.y;
    z[2] += a * (double)wv.z; z[3] += a * (double)wv.w;
  }
  float o[4];
#pragma unroll
  for (int q = 0; q < 4; ++q) {
    int d = dl * 4 + q;
    double hv = z[q] + (double)pwab[d] + (double)pwob[d];
    double bn = (hv - (double)mea[d]) * (1.0 / sqrt((double)varr[d] + 1e-5)) *
                    (double)gam[d] +
                (double)bet[d];
    float bf = (float)bn;
    o[q] = bf > 0.f ? 1.0507009873554805f * bf
                    : 1.7580993408473766f *
                          (__builtin_amdgcn_exp2f(bf * L2E) - 1.0f);
  }
  *(float4*)(h + ((size_t)(b * 256 + i0 + il)) * 128 + dl * 4) = *(float4*)o;

  // pool score partials (fp64, fixed reduction order -> deterministic)
  sScD[il][dl] = (double)o[0] * (double)plw[dl * 4] +
                 (double)o[1] * (double)plw[dl * 4 + 1] +
                 (double)o[2] * (double)plw[dl * 4 + 2] +
                 (double)o[3] * (double)plw[dl * 4 + 3];
  __syncthreads();
  if (tid < 8) {
    double zz = (double)plb[0];
    for (int c = 0; c < 32; ++c) zz += sScD[tid][c];
    scores[b * 256 + i0 + tid] = (float)(1.0 / (1.0 + exp(-zz)));
  }
}

// ---------------- KC: stable top-128 rank + gather h*score ------------------
__global__ __launch_bounds__(1024) void kC_topk(const float* __restrict__ h,
                                                const float* __restrict__ scores,
                                                float* __restrict__ out) {
  const int b = blockIdx.x, tid = threadIdx.x;
  const int t = tid >> 2, c = tid & 3;
  __shared__ float sc[256];
  __shared__ int ipart[256][4];
  __shared__ int sel[128];

  if (c == 0) sc[t] = scores[b * 256 + t];
  __syncthreads();
  {
    const float st = sc[t];
    int r = 0;
    for (int m = c * 64; m < c * 64 + 64; ++m) {
      float sm = sc[m];
      r += (sm > st) || (sm == st && m < t);  // stable descending
    }
    ipart[t][c] = r;
  }
  __syncthreads();
  if (c == 0) {
    int rank = ipart[t][0] + ipart[t][1] + ipart[t][2] + ipart[t][3];
    if (rank < 128) sel[rank] = t;
  }
  __syncthreads();
  const float4* h4 = (const float4*)(h + (size_t)b * 256 * 128);
  float4* o4 = (float4*)(out + (size_t)b * 128 * 128);
#pragma unroll
  for (int r = 0; r < 4; ++r) {
    int v = tid + 1024 * r;
    int row = v >> 5, q = v & 31;
    int src = sel[row];
    float ss = sc[src];
    float4 hv = h4[src * 32 + q];
    float4 ov;
    ov.x = hv.x * ss; ov.y = hv.y * ss; ov.z = hv.z * ss; ov.w = hv.w * ss;
    o4[row * 32 + q] = ov;
  }
}

extern "C" void kernel_launch(void* const* d_in, const int* in_sizes, int n_in,
                              void* d_out, int out_size, void* d_ws, size_t ws_size,
                              hipStream_t stream) {
  const float* x    = (const float*)d_in[0];
  const float* apw  = (const float*)d_in[1];
  const float* apb  = (const float*)d_in[2];
  const float* av   = (const float*)d_in[3];
  const float* pwa  = (const float*)d_in[4];
  const float* pwab = (const float*)d_in[5];
  const float* pwoa = (const float*)d_in[6];
  const float* pwob = (const float*)d_in[7];
  const float* gam  = (const float*)d_in[8];
  const float* bet  = (const float*)d_in[9];
  const float* mea  = (const float*)d_in[10];
  const float* varr = (const float*)d_in[11];
  const float* plw  = (const float*)d_in[12];
  const float* plb  = (const float*)d_in[13];
  float* out = (float*)d_out;

  // ws: gWhi 32K | gWlo 32K | S 16K | Lg 4M | h 2M | scores 16K
  unsigned short* gWhi = (unsigned short*)d_ws;
  unsigned short* gWlo = gWhi + 16384;
  float* S  = (float*)((char*)d_ws + 65536);
  float* Lg = (float*)((char*)d_ws + 81920);
  float* hb = Lg + (size_t)16 * 256 * 256;
  float* sco = hb + (size_t)16 * 256 * 128;

  k0_prep<<<80, 256, 0, stream>>>(apw, gWhi, gWlo, S);
  kA_logits<<<dim3(136, 16), 256, 0, stream>>>(x, gWhi, gWlo, apb, av, Lg, S);
  kB_aggh<<<dim3(32, 16), 256, 0, stream>>>(Lg, S, x, pwa, pwoa, pwab, pwob,
                                            gam, bet, mea, varr, plw, plb, hb, sco);
  kC_topk<<<16, 1024, 0, stream>>>(hb, sco, out);
}